// Round 3
// baseline (145.112 us; speedup 1.0000x reference)
//
#include <hip/hip_runtime.h>
#include <hip/hip_bf16.h>

// BatchHardLoss: out = mean_i log( pos_sum_i * neg_sum_i )
//   W = clip(gamma * Q Q^T, -16, 16)  (clamp provably inert: |W| < 0.4)
//   pos_sum_i = sum_{j: t_j==t_i, j!=i} exp(-W_ij)
//   neg_sum_i = sum_{j: t_j!=t_i}       exp(+W_ij)
//
// R3: R2's symmetric triangular tiling, but ALL global atomics replaced by
// contention-free partial-sum stores. Each (tile,wave) contribution has a
// statically unique slot in partial[128][8192]: row-side of tile (bi,bj)
// wave-col wc -> slot 2*bj+wc; col-side (off-diag) wave-row wr -> slot
// 2*bi+wr. Exactly one writer per slot => plain coalesced stores, no init.
// A 32-block reduce kernel folds 128 partials/row + self-term + log; a
// 1-block kernel finishes the mean.
// Predicted: gemm WRITE 130->~10MB, FETCH 78->~25MB, MfmaUtil ~20%,
// gemm ~35us, total ~85us.

#define BATCH 8192
#define DIM   256
#define NB    64          // 8192/128 tiles per side
#define NSLOT 128         // 2*NB partial slots
#define GAMMA 0.001f

typedef __bf16 bf16x8 __attribute__((ext_vector_type(8)));
typedef float  f32x4  __attribute__((ext_vector_type(4)));

__device__ inline unsigned short f2bf(float f) {
  unsigned u = __float_as_uint(f);
  u += 0x7fffu + ((u >> 16) & 1u);   // RNE (inputs are finite normals)
  return (unsigned short)(u >> 16);
}
__device__ inline float bf2f(unsigned short h) {
  return __uint_as_float(((unsigned)h) << 16);
}

__device__ inline void gload_lds16(const void* src, void* lds) {
  __builtin_amdgcn_global_load_lds(
      (const __attribute__((address_space(1))) void*)src,
      (__attribute__((address_space(3))) void*)lds, 16, 0, 0);
}

// Kernel 1: fp32 -> bf16 convert + bf16-rounded row norms (one wave per row).
__global__ void bhl_prep(const float* __restrict__ in,
                         unsigned short* __restrict__ obf,
                         float* __restrict__ norm2) {
  int t = blockIdx.x * blockDim.x + threadIdx.x;
  float4 v = ((const float4*)in)[t];
  ushort4 o;
  o.x = f2bf(v.x); o.y = f2bf(v.y); o.z = f2bf(v.z); o.w = f2bf(v.w);
  ((ushort4*)obf)[t] = o;
  float bx = bf2f(o.x), by = bf2f(o.y), bz = bf2f(o.z), bw = bf2f(o.w);
  float nrm = bx * bx + by * by + bz * bz + bw * bw;
#pragma unroll
  for (int s = 1; s < 64; s <<= 1) nrm += __shfl_xor(nrm, s, 64);
  if ((threadIdx.x & 63) == 0) norm2[t >> 6] = nrm;
}

// Kernel 2: fused triangular tile GEMM + loss epilogue (atomic-free).
// Block = 256 threads (4 waves, 2x2), tile 128x128, K staged in 4 chunks of 64.
__global__ __launch_bounds__(256, 4) void bhl_gemm(
    const unsigned short* __restrict__ A, const int* __restrict__ tgt,
    float* __restrict__ partP, float* __restrict__ partN) {
  __shared__ __attribute__((aligned(16))) unsigned char smem[32768];
  __shared__ int tRC[256];

  const int tid  = threadIdx.x;
  const int lane = tid & 63, wid = tid >> 6;
  const int wr = wid >> 1, wc = wid & 1;
  const int lc = lane & 15, lg = lane >> 4;

  // ---- triangular decode: linear block id -> (bi, bj), bi <= bj
  int t = blockIdx.x;
  int bi = (int)((129.0f - sqrtf((float)(16641 - 8 * t))) * 0.5f);
  if (bi > NB - 1) bi = NB - 1;
  if (bi < 0) bi = 0;
  while (bi > 0 && bi * NB - (bi * (bi - 1)) / 2 > t) --bi;
  while ((bi + 1) * NB - ((bi + 1) * bi) / 2 <= t) ++bi;
  const int bj = bi + t - (bi * NB - (bi * (bi - 1)) / 2);
  const bool diag = (bi == bj);
  const int rowA0 = bi * 128;   // output rows i
  const int rowB0 = bj * 128;   // output cols j

  int* tR = tRC;
  int* tC = tRC + 128;
  if (tid < 128) tR[tid] = tgt[rowA0 + tid];
  else           tC[tid - 128] = tgt[rowB0 + (tid - 128)];

  f32x4 acc[4][4] = {};   // wave owns 64x64: 4x4 fragments of 16x16

  for (int kc = 0; kc < 4; ++kc) {
    const int k0 = kc * 64;
    // stage A,B k-chunks; LDS dest linear, source col pre-XOR'd (T2 swizzle,
    // both-sides rule #21). 0 bank conflicts verified in R1.
#pragma unroll
    for (int it = 0; it < 4; ++it) {
      int g   = it * 256 + tid;
      int row = g >> 3;
      int cb  = (g & 7) << 4;
      int sc  = (cb ^ ((row & 7) << 4)) >> 1;
      size_t goffA = (size_t)(rowA0 + row) * DIM + k0 + sc;
      size_t goffB = (size_t)(rowB0 + row) * DIM + k0 + sc;
      int lbase = (it * 256 + wid * 64) * 8;
      gload_lds16(A + goffA, (unsigned short*)smem + lbase);
      gload_lds16(A + goffB, (unsigned short*)smem + 8192 + lbase);
    }
    __syncthreads();
#pragma unroll
    for (int kk = 0; kk < 2; ++kk) {
      bf16x8 af[4], bfr[4];
      const int cb0 = kk * 64 + lg * 16;
#pragma unroll
      for (int m = 0; m < 4; ++m) {
        int r = wr * 64 + m * 16 + lc;
        af[m] = *(const bf16x8*)((const char*)smem + r * 128 + (cb0 ^ ((r & 7) << 4)));
      }
#pragma unroll
      for (int n = 0; n < 4; ++n) {
        int r = wc * 64 + n * 16 + lc;
        bfr[n] = *(const bf16x8*)((const char*)smem + 16384 + r * 128 + (cb0 ^ ((r & 7) << 4)));
      }
#pragma unroll
      for (int m = 0; m < 4; ++m)
#pragma unroll
        for (int n = 0; n < 4; ++n)
          acc[m][n] = __builtin_amdgcn_mfma_f32_16x16x32_bf16(af[m], bfr[n], acc[m][n], 0, 0, 0);
    }
    __syncthreads();
  }

  // ---- epilogue. C/D layout: col = lane&15 (=lc), row = lg*4 + reg.
  // Reuse staging LDS (all waves past the last barrier) as per-wave
  // transpose scratch [64][17] f32 (write <=4-way partial, read 2-way=free).
  int tcn[4];
#pragma unroll
  for (int n = 0; n < 4; ++n) tcn[n] = tC[wc * 64 + n * 16 + lc];

  float* myred = ((float*)smem) + wid * (64 * 17);
  float rowN[4][4];
  float colP[4] = {0.f, 0.f, 0.f, 0.f}, colN[4] = {0.f, 0.f, 0.f, 0.f};

#pragma unroll
  for (int m = 0; m < 4; ++m) {
#pragma unroll
    for (int r = 0; r < 4; ++r) {
      const int rl = m * 16 + lg * 4 + r;
      const int ti = tR[wr * 64 + rl];
      float ps = 0.f, ns = 0.f;
#pragma unroll
      for (int n = 0; n < 4; ++n) {
        bool same = (ti == tcn[n]);
        // no clamp needed: |gamma*dot| < 0.4 << 16
        float e = __expf(acc[m][n][r] * (same ? -GAMMA : GAMMA));
        float epos = same ? e : 0.f;
        float eneg = e - epos;
        ps += epos; ns += eneg;
        colP[n] += epos; colN[n] += eneg;
      }
      myred[rl * 17 + lc] = ps;   // ps partials straight to LDS
      rowN[m][r] = ns;
    }
  }
  // transpose-reduce: lane L owns row L of this wave's 64 rows.
  // Row-side slot: 2*bj+wc (unique: only tile (bi,bj) wave-col wc writes it
  // for rows of tile bi).
  const int rslot = 2 * bj + wc;
  asm volatile("s_waitcnt lgkmcnt(0)" ::: "memory");
  {
    float s = 0.f;
#pragma unroll
    for (int k = 0; k < 16; ++k) s += myred[lane * 17 + k];
    partP[(size_t)rslot * BATCH + rowA0 + wr * 64 + lane] = s;
  }
  asm volatile("s_waitcnt lgkmcnt(0)" ::: "memory");
#pragma unroll
  for (int m = 0; m < 4; ++m)
#pragma unroll
    for (int r = 0; r < 4; ++r)
      myred[(m * 16 + lg * 4 + r) * 17 + lc] = rowN[m][r];
  asm volatile("s_waitcnt lgkmcnt(0)" ::: "memory");
  {
    float s = 0.f;
#pragma unroll
    for (int k = 0; k < 16; ++k) s += myred[lane * 17 + k];
    partN[(size_t)rslot * BATCH + rowA0 + wr * 64 + lane] = s;
  }

  // column sums (symmetric counterpart) for off-diagonal tiles.
  // After xor16+xor32, every lane holds the full column sum for col
  // n*16 + lc; lane L wants n = L>>4, i.e. col wc*64 + L. Slot 2*bi+wr
  // (unique: only tile (bi,bj) wave-row wr writes it for rows of tile bj).
  if (!diag) {
#pragma unroll
    for (int n = 0; n < 4; ++n) {
      colP[n] += __shfl_xor(colP[n], 16, 64);
      colP[n] += __shfl_xor(colP[n], 32, 64);
      colN[n] += __shfl_xor(colN[n], 16, 64);
      colN[n] += __shfl_xor(colN[n], 32, 64);
    }
    float p01 = (lane & 16) ? colP[1] : colP[0];
    float p23 = (lane & 16) ? colP[3] : colP[2];
    float vp  = (lane & 32) ? p23 : p01;
    float n01 = (lane & 16) ? colN[1] : colN[0];
    float n23 = (lane & 16) ? colN[3] : colN[2];
    float vn  = (lane & 32) ? n23 : n01;
    const int cslot = 2 * bi + wr;
    partP[(size_t)cslot * BATCH + rowB0 + wc * 64 + lane] = vp;
    partN[(size_t)cslot * BATCH + rowB0 + wc * 64 + lane] = vn;
  }
}

// Kernel 3: per-row fold of 128 partials + self-term + log; block sums out.
__global__ __launch_bounds__(256) void bhl_reduce(
    const float* __restrict__ partP, const float* __restrict__ partN,
    const float* __restrict__ norm2, float* __restrict__ blocksums) {
  __shared__ float red[4];
  const int tid = threadIdx.x;
  const int row = blockIdx.x * 256 + tid;
  float ps = 0.f, ns = 0.f;
#pragma unroll 8
  for (int s = 0; s < NSLOT; ++s) {
    ps += partP[(size_t)s * BATCH + row];
    ns += partN[(size_t)s * BATCH + row];
  }
  float eself = __expf(-GAMMA * norm2[row]);
  float v = __logf((ps - eself) * ns);
#pragma unroll
  for (int sft = 1; sft < 64; sft <<= 1) v += __shfl_xor(v, sft, 64);
  if ((tid & 63) == 0) red[tid >> 6] = v;
  __syncthreads();
  if (tid == 0)
    blocksums[blockIdx.x] = red[0] + red[1] + red[2] + red[3];
}

// Kernel 4: final mean over 32 block sums.
__global__ void bhl_final(const float* __restrict__ blocksums,
                          float* __restrict__ out) {
  float s = (threadIdx.x < 32) ? blocksums[threadIdx.x] : 0.f;
#pragma unroll
  for (int sft = 1; sft < 32; sft <<= 1) s += __shfl_xor(s, sft, 64);
  if (threadIdx.x == 0) out[0] = s * (1.0f / BATCH);
}

extern "C" void kernel_launch(void* const* d_in, const int* in_sizes, int n_in,
                              void* d_out, int out_size, void* d_ws, size_t ws_size,
                              hipStream_t stream) {
  const float* inputs  = (const float*)d_in[0];
  const int*   targets = (const int*)d_in[1];
  float* out = (float*)d_out;

  // ws layout: [0,4MB) bf16 inputs; [4MB,8MB) partP; [8MB,12MB) partN;
  // then norm2 (32KB) and blocksums (128B). ~12.3MB total.
  unsigned short* Abf = (unsigned short*)d_ws;
  float* partP = (float*)((char*)d_ws + (size_t)BATCH * DIM * 2);
  float* partN = partP + (size_t)NSLOT * BATCH;
  float* norm2 = partN + (size_t)NSLOT * BATCH;
  float* bsums = norm2 + BATCH;

  bhl_prep<<<(BATCH * DIM / 4) / 256, 256, 0, stream>>>(inputs, Abf, norm2);
  const int nblk = NB * (NB + 1) / 2;   // 2080 triangular tiles
  bhl_gemm<<<nblk, 256, 0, stream>>>(Abf, targets, partP, partN);
  bhl_reduce<<<BATCH / 256, 256, 0, stream>>>(partP, partN, norm2, bsums);
  bhl_final<<<1, 64, 0, stream>>>(bsums, out);
}

// Round 4
// 111.918 us; speedup vs baseline: 1.2966x; 1.2966x over previous
//
#include <hip/hip_runtime.h>
#include <hip/hip_bf16.h>

// BatchHardLoss: out = mean_i log( pos_sum_i * neg_sum_i )
//   W = clip(gamma * Q Q^T, -16, 16)  (clamp provably inert: |W| < 0.4)
//   pos_sum_i = sum_{j: t_j==t_i, j!=i} exp(-W_ij)
//   neg_sum_i = sum_{j: t_j!=t_i}       exp(+W_ij)
//
// R4: R3 structure, spill fix. R2/R3's __launch_bounds__(256,4) capped
// VGPR+AGPR at 128/wave; acc alone is 64 AGPR -> compiler spilled epilogue
// state to scratch (= the mystery ~100MB FETCH/WRITE, VGPR_Count==64 cap
// tell). Back to __launch_bounds__(256) like R1 (VGPR 76, WRITE 32MB).
// Also: bhl_final folded into bhl_reduce (atomicAdd into zeroed d_out).
// Predicted: gemm FETCH ~20MB, WRITE ~12MB, VGPR ~110, MfmaUtil ~30%,
// gemm ~40us, total ~100us.

#define BATCH 8192
#define DIM   256
#define NB    64          // 8192/128 tiles per side
#define NSLOT 128         // 2*NB partial slots
#define GAMMA 0.001f

typedef __bf16 bf16x8 __attribute__((ext_vector_type(8)));
typedef float  f32x4  __attribute__((ext_vector_type(4)));

__device__ inline unsigned short f2bf(float f) {
  unsigned u = __float_as_uint(f);
  u += 0x7fffu + ((u >> 16) & 1u);   // RNE (inputs are finite normals)
  return (unsigned short)(u >> 16);
}
__device__ inline float bf2f(unsigned short h) {
  return __uint_as_float(((unsigned)h) << 16);
}

__device__ inline void gload_lds16(const void* src, void* lds) {
  __builtin_amdgcn_global_load_lds(
      (const __attribute__((address_space(1))) void*)src,
      (__attribute__((address_space(3))) void*)lds, 16, 0, 0);
}

// Kernel 1: fp32 -> bf16 convert + bf16-rounded row norms (one wave per row).
__global__ void bhl_prep(const float* __restrict__ in,
                         unsigned short* __restrict__ obf,
                         float* __restrict__ norm2) {
  int t = blockIdx.x * blockDim.x + threadIdx.x;
  float4 v = ((const float4*)in)[t];
  ushort4 o;
  o.x = f2bf(v.x); o.y = f2bf(v.y); o.z = f2bf(v.z); o.w = f2bf(v.w);
  ((ushort4*)obf)[t] = o;
  float bx = bf2f(o.x), by = bf2f(o.y), bz = bf2f(o.z), bw = bf2f(o.w);
  float nrm = bx * bx + by * by + bz * bz + bw * bw;
#pragma unroll
  for (int s = 1; s < 64; s <<= 1) nrm += __shfl_xor(nrm, s, 64);
  if ((threadIdx.x & 63) == 0) norm2[t >> 6] = nrm;
}

// Kernel 2: fused triangular tile GEMM + loss epilogue (atomic-free).
// Block = 256 threads (4 waves, 2x2), tile 128x128, K staged in 4 chunks of 64.
// NOTE: no min-waves in launch_bounds — (256,4) caused scratch spills (R2/R3).
__global__ __launch_bounds__(256) void bhl_gemm(
    const unsigned short* __restrict__ A, const int* __restrict__ tgt,
    float* __restrict__ partP, float* __restrict__ partN) {
  __shared__ __attribute__((aligned(16))) unsigned char smem[32768];
  __shared__ int tRC[256];

  const int tid  = threadIdx.x;
  const int lane = tid & 63, wid = tid >> 6;
  const int wr = wid >> 1, wc = wid & 1;
  const int lc = lane & 15, lg = lane >> 4;

  // ---- triangular decode: linear block id -> (bi, bj), bi <= bj
  int t = blockIdx.x;
  int bi = (int)((129.0f - sqrtf((float)(16641 - 8 * t))) * 0.5f);
  if (bi > NB - 1) bi = NB - 1;
  if (bi < 0) bi = 0;
  while (bi > 0 && bi * NB - (bi * (bi - 1)) / 2 > t) --bi;
  while ((bi + 1) * NB - ((bi + 1) * bi) / 2 <= t) ++bi;
  const int bj = bi + t - (bi * NB - (bi * (bi - 1)) / 2);
  const bool diag = (bi == bj);
  const int rowA0 = bi * 128;   // output rows i
  const int rowB0 = bj * 128;   // output cols j

  int* tR = tRC;
  int* tC = tRC + 128;
  if (tid < 128) tR[tid] = tgt[rowA0 + tid];
  else           tC[tid - 128] = tgt[rowB0 + (tid - 128)];

  f32x4 acc[4][4] = {};   // wave owns 64x64: 4x4 fragments of 16x16

  for (int kc = 0; kc < 4; ++kc) {
    const int k0 = kc * 64;
    // stage A,B k-chunks; LDS dest linear, source col pre-XOR'd (T2 swizzle,
    // both-sides rule #21). 0 bank conflicts verified in R1.
#pragma unroll
    for (int it = 0; it < 4; ++it) {
      int g   = it * 256 + tid;
      int row = g >> 3;
      int cb  = (g & 7) << 4;
      int sc  = (cb ^ ((row & 7) << 4)) >> 1;
      size_t goffA = (size_t)(rowA0 + row) * DIM + k0 + sc;
      size_t goffB = (size_t)(rowB0 + row) * DIM + k0 + sc;
      int lbase = (it * 256 + wid * 64) * 8;
      gload_lds16(A + goffA, (unsigned short*)smem + lbase);
      gload_lds16(A + goffB, (unsigned short*)smem + 8192 + lbase);
    }
    __syncthreads();
#pragma unroll
    for (int kk = 0; kk < 2; ++kk) {
      bf16x8 af[4], bfr[4];
      const int cb0 = kk * 64 + lg * 16;
#pragma unroll
      for (int m = 0; m < 4; ++m) {
        int r = wr * 64 + m * 16 + lc;
        af[m] = *(const bf16x8*)((const char*)smem + r * 128 + (cb0 ^ ((r & 7) << 4)));
      }
#pragma unroll
      for (int n = 0; n < 4; ++n) {
        int r = wc * 64 + n * 16 + lc;
        bfr[n] = *(const bf16x8*)((const char*)smem + 16384 + r * 128 + (cb0 ^ ((r & 7) << 4)));
      }
#pragma unroll
      for (int m = 0; m < 4; ++m)
#pragma unroll
        for (int n = 0; n < 4; ++n)
          acc[m][n] = __builtin_amdgcn_mfma_f32_16x16x32_bf16(af[m], bfr[n], acc[m][n], 0, 0, 0);
    }
    __syncthreads();
  }

  // ---- epilogue. C/D layout: col = lane&15 (=lc), row = lg*4 + reg.
  // Reuse staging LDS (all waves past the last barrier) as per-wave
  // transpose scratch [64][17] f32 (write <=4-way partial, read 2-way=free).
  int tcn[4];
#pragma unroll
  for (int n = 0; n < 4; ++n) tcn[n] = tC[wc * 64 + n * 16 + lc];

  float* myred = ((float*)smem) + wid * (64 * 17);
  float rowN[4][4];
  float colP[4] = {0.f, 0.f, 0.f, 0.f}, colN[4] = {0.f, 0.f, 0.f, 0.f};

#pragma unroll
  for (int m = 0; m < 4; ++m) {
#pragma unroll
    for (int r = 0; r < 4; ++r) {
      const int rl = m * 16 + lg * 4 + r;
      const int ti = tR[wr * 64 + rl];
      float ps = 0.f, ns = 0.f;
#pragma unroll
      for (int n = 0; n < 4; ++n) {
        bool same = (ti == tcn[n]);
        // no clamp needed: |gamma*dot| < 0.4 << 16
        float e = __expf(acc[m][n][r] * (same ? -GAMMA : GAMMA));
        float epos = same ? e : 0.f;
        float eneg = e - epos;
        ps += epos; ns += eneg;
        colP[n] += epos; colN[n] += eneg;
      }
      myred[rl * 17 + lc] = ps;   // ps partials straight to LDS
      rowN[m][r] = ns;
    }
  }
  // transpose-reduce: lane L owns row L of this wave's 64 rows.
  // Row-side slot: 2*bj+wc (unique writer per slot).
  const int rslot = 2 * bj + wc;
  asm volatile("s_waitcnt lgkmcnt(0)" ::: "memory");
  {
    float s = 0.f;
#pragma unroll
    for (int k = 0; k < 16; ++k) s += myred[lane * 17 + k];
    partP[(size_t)rslot * BATCH + rowA0 + wr * 64 + lane] = s;
  }
  asm volatile("s_waitcnt lgkmcnt(0)" ::: "memory");
#pragma unroll
  for (int m = 0; m < 4; ++m)
#pragma unroll
    for (int r = 0; r < 4; ++r)
      myred[(m * 16 + lg * 4 + r) * 17 + lc] = rowN[m][r];
  asm volatile("s_waitcnt lgkmcnt(0)" ::: "memory");
  {
    float s = 0.f;
#pragma unroll
    for (int k = 0; k < 16; ++k) s += myred[lane * 17 + k];
    partN[(size_t)rslot * BATCH + rowA0 + wr * 64 + lane] = s;
  }

  // column sums (symmetric counterpart) for off-diagonal tiles.
  // After xor16+xor32 every lane holds the col sum for col n*16+lc; lane L
  // selects n = L>>4 so it owns col wc*64+L. Slot 2*bi+wr (unique writer).
  if (!diag) {
#pragma unroll
    for (int n = 0; n < 4; ++n) {
      colP[n] += __shfl_xor(colP[n], 16, 64);
      colP[n] += __shfl_xor(colP[n], 32, 64);
      colN[n] += __shfl_xor(colN[n], 16, 64);
      colN[n] += __shfl_xor(colN[n], 32, 64);
    }
    float p01 = (lane & 16) ? colP[1] : colP[0];
    float p23 = (lane & 16) ? colP[3] : colP[2];
    float vp  = (lane & 32) ? p23 : p01;
    float n01 = (lane & 16) ? colN[1] : colN[0];
    float n23 = (lane & 16) ? colN[3] : colN[2];
    float vn  = (lane & 32) ? n23 : n01;
    const int cslot = 2 * bi + wr;
    partP[(size_t)cslot * BATCH + rowB0 + wc * 64 + lane] = vp;
    partN[(size_t)cslot * BATCH + rowB0 + wc * 64 + lane] = vn;
  }
}

// Kernel 3: per-row fold of 128 partials + self-term + log; scaled block
// sums atomically accumulated into d_out (zeroed via hipMemsetAsync).
__global__ __launch_bounds__(256) void bhl_reduce(
    const float* __restrict__ partP, const float* __restrict__ partN,
    const float* __restrict__ norm2, float* __restrict__ out) {
  __shared__ float red[4];
  const int tid = threadIdx.x;
  const int row = blockIdx.x * 256 + tid;
  float ps = 0.f, ns = 0.f;
#pragma unroll 8
  for (int s = 0; s < NSLOT; ++s) {
    ps += partP[(size_t)s * BATCH + row];
    ns += partN[(size_t)s * BATCH + row];
  }
  float eself = __expf(-GAMMA * norm2[row]);
  float v = __logf((ps - eself) * ns);
#pragma unroll
  for (int sft = 1; sft < 64; sft <<= 1) v += __shfl_xor(v, sft, 64);
  if ((tid & 63) == 0) red[tid >> 6] = v;
  __syncthreads();
  if (tid == 0)
    atomicAdd(out, (red[0] + red[1] + red[2] + red[3]) * (1.0f / BATCH));
}

extern "C" void kernel_launch(void* const* d_in, const int* in_sizes, int n_in,
                              void* d_out, int out_size, void* d_ws, size_t ws_size,
                              hipStream_t stream) {
  const float* inputs  = (const float*)d_in[0];
  const int*   targets = (const int*)d_in[1];
  float* out = (float*)d_out;

  // ws layout: [0,4MB) bf16 inputs; [4MB,8MB) partP; [8MB,12MB) partN;
  // then norm2 (32KB). ~12.1MB total.
  unsigned short* Abf = (unsigned short*)d_ws;
  float* partP = (float*)((char*)d_ws + (size_t)BATCH * DIM * 2);
  float* partN = partP + (size_t)NSLOT * BATCH;
  float* norm2 = partN + (size_t)NSLOT * BATCH;

  hipMemsetAsync(out, 0, sizeof(float), stream);
  bhl_prep<<<(BATCH * DIM / 4) / 256, 256, 0, stream>>>(inputs, Abf, norm2);
  const int nblk = NB * (NB + 1) / 2;   // 2080 triangular tiles
  bhl_gemm<<<nblk, 256, 0, stream>>>(Abf, targets, partP, partN);
  bhl_reduce<<<BATCH / 256, 256, 0, stream>>>(partP, partN, norm2, out);
}